// Round 1
// baseline (412.131 us; speedup 1.0000x reference)
//
#include <hip/hip_runtime.h>
#include <hip/hip_bf16.h>
#include <stdint.h>

// ---------------------------------------------------------------------------
// AttentionActPrune: B=16, S=1024, D=1024, H=16, DH=64.
// Inputs/outputs FP32. Compute: convert to bf16, fused QKV gemm (256^2 tile,
// 8-phase counted-vmcnt schedule, Q pre-scaled by log2(e)/8) -> V transpose
// -> attention v5 -> out gemm (fp32 out, same 256^2 8-phase kernel).
// ---------------------------------------------------------------------------

typedef short bf16x8 __attribute__((ext_vector_type(8)));
typedef float f32x4 __attribute__((ext_vector_type(4)));
typedef unsigned short ushort_t;
typedef ushort_t us8 __attribute__((ext_vector_type(8)));

__device__ __forceinline__ ushort_t f2b(float f) {
    unsigned x;
    __builtin_memcpy(&x, &f, 4);
    unsigned r = (x + 0x7fffu + ((x >> 16) & 1u)) >> 16;
    return (ushort_t)r;
}

__device__ __forceinline__ void glds16(const void* g, void* l) {
    __builtin_amdgcn_global_load_lds(
        (const __attribute__((address_space(1))) void*)g,
        (__attribute__((address_space(3))) void*)l, 16, 0, 0);
}

#define MFMA16(a, b, c) __builtin_amdgcn_mfma_f32_16x16x32_bf16((a), (b), (c), 0, 0, 0)

// ---------------------------------------------------------------------------
// fp32 -> bf16 (RNE), 8 elems/thread. grid.y selects among 4 src/dst pairs.
// ---------------------------------------------------------------------------
__global__ __launch_bounds__(256, 8) void cvt4_kernel(
    const float* __restrict__ s0, const float* __restrict__ s1,
    const float* __restrict__ s2, const float* __restrict__ s3,
    ushort_t* __restrict__ d0, ushort_t* __restrict__ d1,
    ushort_t* __restrict__ d2, ushort_t* __restrict__ d3, int n8)
{
    const float* in = (blockIdx.y == 0) ? s0 : (blockIdx.y == 1) ? s1
                       : (blockIdx.y == 2) ? s2 : s3;
    ushort_t* out = (blockIdx.y == 0) ? d0 : (blockIdx.y == 1) ? d1
                       : (blockIdx.y == 2) ? d2 : d3;
    int i = blockIdx.x * 256 + threadIdx.x;
    if (i >= n8) return;
    const float4* p = (const float4*)in + (size_t)i * 2;
    float4 a = p[0], b = p[1];
    us8 v;
    v[0] = f2b(a.x); v[1] = f2b(a.y); v[2] = f2b(a.z); v[3] = f2b(a.w);
    v[4] = f2b(b.x); v[5] = f2b(b.y); v[6] = f2b(b.z); v[7] = f2b(b.w);
    *((us8*)out + i) = v;
}

__global__ __launch_bounds__(256, 8) void cvt1_kernel(
    const float* __restrict__ in, ushort_t* __restrict__ out, int n8)
{
    int i = blockIdx.x * 256 + threadIdx.x;
    if (i >= n8) return;
    const float4* p = (const float4*)in + (size_t)i * 2;
    float4 a = p[0], b = p[1];
    us8 v;
    v[0] = f2b(a.x); v[1] = f2b(a.y); v[2] = f2b(a.z); v[3] = f2b(a.w);
    v[4] = f2b(b.x); v[5] = f2b(b.y); v[6] = f2b(b.z); v[7] = f2b(b.w);
    *((us8*)out + i) = v;
}

// ---------------------------------------------------------------------------
// 256x256-tile GEMM with bias+scale: C[m,n] = (sum_k A[m,k]*W[n,k] + b[n])*s
// 512 threads = 8 waves (2 M x 4 N), per-wave output 128x64, MFMA 16x16x32.
// BK=64 split into two k-halves of 32. LDS: 2 buffers x 4 regions
// (A-k0, A-k1, B-k0, B-k1) x 16KB = 128KB. Even K-tiles live in buf0, odd in
// buf1 (static). 8 phases per 2 K-tiles; each phase: {ds_read frags, issue
// one region's global_load_lds, barrier, setprio(1), 16 MFMA, setprio(0),
// barrier}. vmcnt(4) only at phases 4 and 8 (counted, never 0 mid-loop).
//
// Race-freedom (barrier-granular): a region staged at phase p had its last
// ds_read at phase <= p-1; those reads are consumed by that phase's MFMAs
// (compiler lgkmcnt before use), which precede the phase-end barrier
// (sched_barrier(0) pins them), which precedes p's glds issue.
// Completion: vmcnt(4)@P4 + barrier => stages issued <= P2 visible at P5;
// vmcnt(4)@P8 => stages <= P6 visible at next P1. Every region's first read
// is covered (A-k1/B-k1 of odd tile staged P1/P2, read P7/P8: covered by P4's
// point; all others have >= 2 phases of slack).
// ---------------------------------------------------------------------------
template <bool OUTF>
__global__ __launch_bounds__(512) void gemm256_kernel(
    const ushort_t* __restrict__ A,
    const ushort_t* __restrict__ W0, const ushort_t* __restrict__ W1, const ushort_t* __restrict__ W2,
    const float* __restrict__ b0, const float* __restrict__ b1, const float* __restrict__ b2,
    void* __restrict__ C0, void* __restrict__ C1, void* __restrict__ C2,
    float s0, float s1, float s2, int N, int K)
{
    const ushort_t* W = (blockIdx.z == 0) ? W0 : ((blockIdx.z == 1) ? W1 : W2);
    const float* bias = (blockIdx.z == 0) ? b0 : ((blockIdx.z == 1) ? b1 : b2);
    void* C = (blockIdx.z == 0) ? C0 : ((blockIdx.z == 1) ? C1 : C2);
    const float scale = (blockIdx.z == 0) ? s0 : ((blockIdx.z == 1) ? s1 : s2);

    // [buf][region: 0=A-k0, 1=A-k1, 2=B-k0, 3=B-k1][256 rows x 32 k] bf16
    __shared__ ushort_t lds[2][4][256 * 32];

    const int tid = threadIdx.x;
    const int lane = tid & 63;
    const int wave = tid >> 6;
    const int wr = wave >> 2;       // 0..1 (M)
    const int wc = wave & 3;        // 0..3 (N)
    const int rl = lane & 15;       // operand row within 16
    const int ck = lane >> 4;       // k-chunk (8 bf16)

    // XCD-aware bijective swizzle over the (x,y) plane (nwg % 8 == 0)
    const int gx = gridDim.x;
    const int flat = blockIdx.y * gx + blockIdx.x;
    const int cpx = (gx * gridDim.y) >> 3;
    const int swz = (flat & 7) * cpx + (flat >> 3);
    const int bm = (swz % gx) * 256;
    const int bn = (swz / gx) * 256;

    const ushort_t* Ag = A + (size_t)bm * K;
    const ushort_t* Bg = W + (size_t)bn * K;

    // staging: 1024 16B chunks per 16KB region; chunk q -> row q>>2, col (q&3)*8
    const int q0 = tid, q1 = 512 + tid;
    const int sr0 = q0 >> 2, sc0 = (q0 & 3) * 8;
    const int sr1 = q1 >> 2, sc1 = (q1 & 3) * 8;

#define STG(gbase, kcol, dst) do { \
    glds16((gbase) + (size_t)sr0 * K + (kcol) + sc0, (dst) + q0 * 8); \
    glds16((gbase) + (size_t)sr1 * K + (kcol) + sc1, (dst) + q1 * 8); } while (0)

#define BARRIER() do { \
    __builtin_amdgcn_sched_barrier(0); \
    asm volatile("s_barrier" ::: "memory"); \
    __builtin_amdgcn_sched_barrier(0); } while (0)

#define VMCNT(n) asm volatile("s_waitcnt vmcnt(" #n ")" ::: "memory")

    f32x4 acc[8][4] = {};
    bf16x8 af[8], bfr[2];

    const int aoff = (wr * 128 + rl) * 32 + ck * 8;
    const int boff = (wc * 64 + rl) * 32 + ck * 8;

#define LDA(buf, kh) do { _Pragma("unroll") \
    for (int mi = 0; mi < 8; ++mi) \
        af[mi] = *(const bf16x8*)(&lds[buf][kh][0] + aoff + mi * 512); } while (0)
#define LDB(buf, kh, nb) do { \
    bfr[0] = *(const bf16x8*)(&lds[buf][2 + (kh)][0] + boff + (nb) * 1024); \
    bfr[1] = *(const bf16x8*)(&lds[buf][2 + (kh)][0] + boff + (nb) * 1024 + 512); } while (0)
#define MM(nb) do { __builtin_amdgcn_s_setprio(1); _Pragma("unroll") \
    for (int mi = 0; mi < 8; ++mi) { \
        acc[mi][2*(nb)]   = MFMA16(af[mi], bfr[0], acc[mi][2*(nb)]); \
        acc[mi][2*(nb)+1] = MFMA16(af[mi], bfr[1], acc[mi][2*(nb)+1]); } \
    __builtin_amdgcn_s_setprio(0); } while (0)

    // prologue: tile0 all 4 regions -> buf0; tile1 k0 regions -> buf1 (last)
    STG(Ag, 0,  &lds[0][0][0]);
    STG(Bg, 0,  &lds[0][2][0]);
    STG(Ag, 32, &lds[0][1][0]);
    STG(Bg, 32, &lds[0][3][0]);
    STG(Ag, 64, &lds[1][0][0]);
    STG(Bg, 64, &lds[1][2][0]);
    VMCNT(4);               // tile0 fully landed; tile1-k0 still in flight
    BARRIER();

#pragma unroll 1
    for (int i = 0; i < 7; ++i) {
        const int t = 2 * i;
        const int kc1 = (t + 1) * 64, kc2 = (t + 2) * 64, kc3 = (t + 3) * 64;
        // P1: compute t.k0 x n01 | stage (t+1).A-k1
        LDA(0, 0); LDB(0, 0, 0);
        STG(Ag, kc1 + 32, &lds[1][1][0]);
        BARRIER(); MM(0); BARRIER();
        // P2: compute t.k0 x n23 | stage (t+1).B-k1
        LDB(0, 0, 1);
        STG(Bg, kc1 + 32, &lds[1][3][0]);
        BARRIER(); MM(1); BARRIER();
        // P3: compute t.k1 x n01 | stage (t+2).A-k0
        LDA(0, 1); LDB(0, 1, 0);
        STG(Ag, kc2, &lds[0][0][0]);
        BARRIER(); MM(0); BARRIER();
        // P4: compute t.k1 x n23 | stage (t+2).B-k0 | vmcnt(4)
        LDB(0, 1, 1);
        STG(Bg, kc2, &lds[0][2][0]);
        VMCNT(4);
        BARRIER(); MM(1); BARRIER();
        // P5: compute (t+1).k0 x n01 | stage (t+2).A-k1
        LDA(1, 0); LDB(1, 0, 0);
        STG(Ag, kc2 + 32, &lds[0][1][0]);
        BARRIER(); MM(0); BARRIER();
        // P6: compute (t+1).k0 x n23 | stage (t+2).B-k1
        LDB(1, 0, 1);
        STG(Bg, kc2 + 32, &lds[0][3][0]);
        BARRIER(); MM(1); BARRIER();
        // P7: compute (t+1).k1 x n01 | stage (t+3).A-k0
        LDA(1, 1); LDB(1, 1, 0);
        STG(Ag, kc3, &lds[1][0][0]);
        BARRIER(); MM(0); BARRIER();
        // P8: compute (t+1).k1 x n23 | stage (t+3).B-k0 | vmcnt(4)
        LDB(1, 1, 1);
        STG(Bg, kc3, &lds[1][2][0]);
        VMCNT(4);
        BARRIER(); MM(1); BARRIER();
    }

    // tail: tiles 14 (buf0) and 15 (buf1); only t15.k1 still needs staging
    {
        const int kc15 = 15 * 64;
        LDA(0, 0); LDB(0, 0, 0);
        STG(Ag, kc15 + 32, &lds[1][1][0]);
        BARRIER(); MM(0); BARRIER();
        LDB(0, 0, 1);
        STG(Bg, kc15 + 32, &lds[1][3][0]);
        BARRIER(); MM(1); BARRIER();
        LDA(0, 1); LDB(0, 1, 0);
        BARRIER(); MM(0); BARRIER();
        LDB(0, 1, 1);
        VMCNT(0);           // drain: t15.k1 (staged P1/P2 above) now visible
        BARRIER(); MM(1); BARRIER();
        // tile 15: everything resident, no barriers needed
        LDA(1, 0); LDB(1, 0, 0); MM(0);
        LDB(1, 0, 1); MM(1);
        LDA(1, 1); LDB(1, 1, 0); MM(0);
        LDB(1, 1, 1); MM(1);
    }

    // epilogue: C/D 16x16 layout col = lane&15, row = 4*(lane>>4)+reg
#pragma unroll
    for (int ni = 0; ni < 4; ++ni) {
        const int col = bn + wc * 64 + ni * 16 + rl;
        const float bv = bias[col];
#pragma unroll
        for (int mi = 0; mi < 8; ++mi) {
            const int rbase = bm + wr * 128 + mi * 16 + ck * 4;
#pragma unroll
            for (int r = 0; r < 4; ++r) {
                float v = (acc[mi][ni][r] + bv) * scale;
                if (OUTF)
                    ((float*)C)[(size_t)(rbase + r) * N + col] = v;
                else
                    ((ushort_t*)C)[(size_t)(rbase + r) * N + col] = f2b(v);
            }
        }
    }
#undef STG
#undef BARRIER
#undef VMCNT
#undef LDA
#undef LDB
#undef MM
}

// ---------------------------------------------------------------------------
// V transpose: V[b*1024+s][h*64+d] -> Vt[(b*16+h)*64+d][s]  (bf16)
// ---------------------------------------------------------------------------
__global__ __launch_bounds__(256, 4) void transpose_v_kernel(
    const ushort_t* __restrict__ V, ushort_t* __restrict__ Vt)
{
    __shared__ ushort_t t[64 * 65];
    const int bh = blockIdx.x;
    const int st = blockIdx.y;
    const int b = bh >> 4, h = bh & 15;
    const int tid = threadIdx.x;

#pragma unroll
    for (int i = 0; i < 16; ++i) {
        int e = i * 256 + tid;
        int s = e >> 6, d = e & 63;
        t[s * 65 + d] = V[(size_t)(b * 1024 + st * 64 + s) * 1024 + h * 64 + d];
    }
    __syncthreads();
#pragma unroll
    for (int i = 0; i < 16; ++i) {
        int e = i * 256 + tid;
        int d = e >> 6, s = e & 63;
        Vt[(size_t)(bh * 64 + d) * 1024 + st * 64 + s] = t[s * 65 + d];
    }
}

// ---------------------------------------------------------------------------
// Attention v5: per block (bh, qtile of 128 rows). 4 waves x 32 q-rows
// (parallel m-groups). Double-buffered K/V staging. Row sums via MFMA
// against a constant all-ones B fragment. Q pre-scaled by log2(e)/8.
// ---------------------------------------------------------------------------
__global__ __launch_bounds__(256, 2) void attn_kernel(
    const ushort_t* __restrict__ Q, const ushort_t* __restrict__ K,
    const ushort_t* __restrict__ Vt, ushort_t* __restrict__ ctx)
{
    __shared__ ushort_t Ks[2][64 * 64];     // [kv][d] swizzled chunks
    __shared__ ushort_t Vs[2][64 * 64];     // [d][kv] swizzled chunks
    __shared__ ushort_t Ps[4][32 * 72];     // per-wave P: [m 0..31][k 0..63]

    const int bh = blockIdx.x;   // 0..255
    const int qt = blockIdx.y;   // 0..7
    const int b = bh >> 4, h = bh & 15;
    const int tid = threadIdx.x;
    const int lane = tid & 63;
    const int wave = tid >> 6;
    const int q = lane >> 4;
    const int ml = lane & 15;

    const int cid0 = tid;            // staging chunk ids
    const int cid1 = 256 + tid;
    const int r0 = cid0 >> 3, sc0 = (cid0 & 7) ^ (r0 & 7);
    const int r1 = cid1 >> 3, sc1 = (cid1 & 7) ^ (r1 & 7);
    const ushort_t* Kbase = K + (size_t)(b * 1024) * 1024 + h * 64;
    const ushort_t* Vbase = Vt + (size_t)(bh * 64) * 1024;

    // Q fragments (B operand of S^T mfma)
    bf16x8 qf[2][2];
#pragma unroll
    for (int mg = 0; mg < 2; ++mg) {
        int row = b * 1024 + qt * 128 + wave * 32 + mg * 16 + ml;
        const ushort_t* qp = Q + (size_t)row * 1024 + h * 64;
        qf[mg][0] = *(const bf16x8*)(qp + q * 8);
        qf[mg][1] = *(const bf16x8*)(qp + 32 + q * 8);
    }

    bf16x8 ones;
#pragma unroll
    for (int i = 0; i < 8; ++i) ones[i] = (short)0x3F80;  // bf16 1.0

    f32x4 o[2][4] = {};
    f32x4 ls[2] = {};
    ushort_t* Pw = Ps[wave];

    // prologue: stage kt=0 into buffer 0
    glds16(Kbase + (size_t)r0 * 1024 + sc0 * 8, Ks[0] + cid0 * 8);
    glds16(Vbase + (size_t)r0 * 1024 + sc0 * 8, Vs[0] + cid0 * 8);
    glds16(Kbase + (size_t)r1 * 1024 + sc1 * 8, Ks[0] + cid1 * 8);
    glds16(Vbase + (size_t)r1 * 1024 + sc1 * 8, Vs[0] + cid1 * 8);

    for (int kt = 0; kt < 16; ++kt) {
        const int cur = kt & 1, nxt = cur ^ 1;
        __syncthreads();   // drains this wave's loads for buf[cur]
        if (kt + 1 < 16) {
            const ushort_t* Kn = Kbase + (size_t)(kt + 1) * 64 * 1024;
            const ushort_t* Vn = Vbase + (kt + 1) * 64;
            glds16(Kn + (size_t)r0 * 1024 + sc0 * 8, Ks[nxt] + cid0 * 8);
            glds16(Vn + (size_t)r0 * 1024 + sc0 * 8, Vs[nxt] + cid0 * 8);
            glds16(Kn + (size_t)r1 * 1024 + sc1 * 8, Ks[nxt] + cid1 * 8);
            glds16(Vn + (size_t)r1 * 1024 + sc1 * 8, Vs[nxt] + cid1 * 8);
        }
        const ushort_t* Kc = Ks[cur];
        const ushort_t* Vc = Vs[cur];

        // S^T = K Q^T: C col=m(=ml), row=k_local=q*4+r
#pragma unroll
        for (int n = 0; n < 4; ++n) {
            int row = n * 16 + ml;
            int c0 = q ^ (row & 7);
            int c1 = (4 + q) ^ (row & 7);
            bf16x8 k0 = *(const bf16x8*)(Kc + row * 64 + c0 * 8);
            bf16x8 k1 = *(const bf16x8*)(Kc + row * 64 + c1 * 8);
#pragma unroll
            for (int mg = 0; mg < 2; ++mg) {
                f32x4 z = {};
                z = MFMA16(k0, qf[mg][0], z);
                z = MFMA16(k1, qf[mg][1], z);
                float p0 = __builtin_amdgcn_exp2f(z[0]);
                float p1 = __builtin_amdgcn_exp2f(z[1]);
                float p2 = __builtin_amdgcn_exp2f(z[2]);
                float p3 = __builtin_amdgcn_exp2f(z[3]);
                __hip_bfloat162 h01 = __float22bfloat162_rn(make_float2(p0, p1));
                __hip_bfloat162 h23 = __float22bfloat162_rn(make_float2(p2, p3));
                uint2 dd;
                __builtin_memcpy(&dd.x, &h01, 4);
                __builtin_memcpy(&dd.y, &h23, 4);
                *(uint2*)(Pw + (mg * 16 + ml) * 72 + n * 16 + q * 4) = dd;
            }
        }

        // P A-frags + PV + ones-sum
#pragma unroll
        for (int mg = 0; mg < 2; ++mg) {
            bf16x8 pf0 = *(const bf16x8*)(Pw + (mg * 16 + ml) * 72 + q * 8);
            bf16x8 pf1 = *(const bf16x8*)(Pw + (mg * 16 + ml) * 72 + 32 + q * 8);
            ls[mg] = MFMA16(pf0, ones, ls[mg]);
            ls[mg] = MFMA16(pf1, ones, ls[mg]);
#pragma unroll
            for (int n = 0; n < 4; ++n) {
                int row = n * 16 + ml;
                int c0 = q ^ (row & 7);
                int c1 = (4 + q) ^ (row & 7);
                bf16x8 v0 = *(const bf16x8*)(Vc + row * 64 + c0 * 8);
                bf16x8 v1 = *(const bf16x8*)(Vc + row * 64 + c1 * 8);
                o[mg][n] = MFMA16(pf0, v0, o[mg][n]);
                o[mg][n] = MFMA16(pf1, v1, o[mg][n]);
            }
        }
    }

    // normalize: ls[mg][r] is the full row sum for m=q*4+r — in-lane.
    const int orow_base = b * 1024 + qt * 128 + wave * 32;
#pragma unroll
    for (int mg = 0; mg < 2; ++mg) {
#pragma unroll
        for (int r = 0; r < 4; ++r) {
            float lv = 1.0f / ls[mg][r];
            int orow = orow_base + mg * 16 + q * 4 + r;
#pragma unroll
            for (int n = 0; n < 4; ++n) {
                ctx[(size_t)orow * 1024 + h * 64 + n * 16 + ml] =
                    f2b(o[mg][n][r] * lv);
            }
        }
    }
}

// ---------------------------------------------------------------------------
extern "C" void kernel_launch(void* const* d_in, const int* in_sizes, int n_in,
                              void* d_out, int out_size, void* d_ws, size_t ws_size,
                              hipStream_t stream)
{
    const float* X  = (const float*)d_in[0];
    const float* Wq = (const float*)d_in[1];
    const float* bq = (const float*)d_in[2];
    const float* Wk = (const float*)d_in[3];
    const float* bk = (const float*)d_in[4];
    const float* Wv = (const float*)d_in[5];
    const float* bv = (const float*)d_in[6];
    const float* Wo = (const float*)d_in[7];
    const float* bo = (const float*)d_in[8];

    const int D = 1024;
    const int M = in_sizes[0] / D;       // 16384
    const int Bb = M / 1024;             // 16 batches
    const size_t MD = (size_t)M * D;
    const size_t DD = (size_t)D * D;

    ushort_t* ws  = (ushort_t*)d_ws;
    ushort_t* Xbf = ws;                  // -> reused as Vt after QKV
    ushort_t* Qb  = ws + MD;
    ushort_t* Kb  = ws + 2 * MD;
    ushort_t* Vb  = ws + 3 * MD;         // -> reused as ctx after transpose
    ushort_t* Wqb = ws + 4 * MD;
    ushort_t* Wkb = Wqb + DD;
    ushort_t* Wvb = Wkb + DD;
    ushort_t* Wob = Wvb + DD;
    ushort_t* Vtb = Xbf;
    ushort_t* ctx = Vb;

    dim3 blk(256);
    dim3 blk512(512);

    cvt1_kernel<<<(int)(MD / 8 / 256), blk, 0, stream>>>(X, Xbf, (int)(MD / 8));
    cvt4_kernel<<<dim3((int)(DD / 8 / 256), 4), blk, 0, stream>>>(
        Wq, Wk, Wv, Wo, Wqb, Wkb, Wvb, Wob, (int)(DD / 8));

    // Q pre-scaled by log2(e)/sqrt(64) so attention uses exp2 directly.
    const float qscale = 1.4426950408889634f * 0.125f;
    dim3 gqkv(M / 256, D / 256, 3);
    gemm256_kernel<false><<<gqkv, blk512, 0, stream>>>(Xbf, Wqb, Wkb, Wvb,
                                                       bq, bk, bv,
                                                       Qb, Kb, Vb,
                                                       qscale, 1.0f, 1.0f, D, D);

    transpose_v_kernel<<<dim3(Bb * 16, 16), blk, 0, stream>>>(Vb, Vtb);

    attn_kernel<<<dim3(Bb * 16, 8), blk, 0, stream>>>(Qb, Kb, Vtb, ctx);

    dim3 go(M / 256, D / 256, 1);
    gemm256_kernel<true><<<go, blk512, 0, stream>>>(ctx, Wob, Wob, Wob,
                                                    bo, bo, bo,
                                                    d_out, d_out, d_out,
                                                    1.0f, 1.0f, 1.0f, D, D);
}

// Round 2
// 398.686 us; speedup vs baseline: 1.0337x; 1.0337x over previous
//
#include <hip/hip_runtime.h>
#include <hip/hip_bf16.h>
#include <stdint.h>

// ---------------------------------------------------------------------------
// AttentionActPrune: B=16, S=1024, D=1024, H=16, DH=64.
// Inputs/outputs FP32. Compute: convert to bf16, fused QKV gemm (256^2 tile,
// 8-phase counted-vmcnt schedule, 32x32 MFMA, conflict-free chunk-rotated
// LDS, Q pre-scaled by log2(e)/8) -> V transpose -> attention v5 -> out gemm.
// ---------------------------------------------------------------------------

typedef short bf16x8 __attribute__((ext_vector_type(8)));
typedef float f32x4 __attribute__((ext_vector_type(4)));
typedef float f32x16 __attribute__((ext_vector_type(16)));
typedef unsigned short ushort_t;
typedef ushort_t us8 __attribute__((ext_vector_type(8)));

__device__ __forceinline__ ushort_t f2b(float f) {
    unsigned x;
    __builtin_memcpy(&x, &f, 4);
    unsigned r = (x + 0x7fffu + ((x >> 16) & 1u)) >> 16;
    return (ushort_t)r;
}

__device__ __forceinline__ void glds16(const void* g, void* l) {
    __builtin_amdgcn_global_load_lds(
        (const __attribute__((address_space(1))) void*)g,
        (__attribute__((address_space(3))) void*)l, 16, 0, 0);
}

#define MFMA16(a, b, c) __builtin_amdgcn_mfma_f32_16x16x32_bf16((a), (b), (c), 0, 0, 0)
#define MFMA32(a, b, c) __builtin_amdgcn_mfma_f32_32x32x16_bf16((a), (b), (c), 0, 0, 0)

// ---------------------------------------------------------------------------
// fp32 -> bf16 (RNE), 8 elems/thread. grid.y selects among 4 src/dst pairs.
// ---------------------------------------------------------------------------
__global__ __launch_bounds__(256, 8) void cvt4_kernel(
    const float* __restrict__ s0, const float* __restrict__ s1,
    const float* __restrict__ s2, const float* __restrict__ s3,
    ushort_t* __restrict__ d0, ushort_t* __restrict__ d1,
    ushort_t* __restrict__ d2, ushort_t* __restrict__ d3, int n8)
{
    const float* in = (blockIdx.y == 0) ? s0 : (blockIdx.y == 1) ? s1
                       : (blockIdx.y == 2) ? s2 : s3;
    ushort_t* out = (blockIdx.y == 0) ? d0 : (blockIdx.y == 1) ? d1
                       : (blockIdx.y == 2) ? d2 : d3;
    int i = blockIdx.x * 256 + threadIdx.x;
    if (i >= n8) return;
    const float4* p = (const float4*)in + (size_t)i * 2;
    float4 a = p[0], b = p[1];
    us8 v;
    v[0] = f2b(a.x); v[1] = f2b(a.y); v[2] = f2b(a.z); v[3] = f2b(a.w);
    v[4] = f2b(b.x); v[5] = f2b(b.y); v[6] = f2b(b.z); v[7] = f2b(b.w);
    *((us8*)out + i) = v;
}

__global__ __launch_bounds__(256, 8) void cvt1_kernel(
    const float* __restrict__ in, ushort_t* __restrict__ out, int n8)
{
    int i = blockIdx.x * 256 + threadIdx.x;
    if (i >= n8) return;
    const float4* p = (const float4*)in + (size_t)i * 2;
    float4 a = p[0], b = p[1];
    us8 v;
    v[0] = f2b(a.x); v[1] = f2b(a.y); v[2] = f2b(a.z); v[3] = f2b(a.w);
    v[4] = f2b(b.x); v[5] = f2b(b.y); v[6] = f2b(b.z); v[7] = f2b(b.w);
    *((us8*)out + i) = v;
}

// ---------------------------------------------------------------------------
// 256x256-tile GEMM with bias+scale: C[m,n] = (sum_k A[m,k]*W[n,k] + b[n])*s
// 512 threads = 8 waves (2 M x 4 N), per-wave output 128x64, MFMA 32x32x16.
// BK=64 as two 32-k regions. LDS: 2 buf x 4 regions (Ak0,Ak1,Bk0,Bk1) x
// [256 rows][32 k] bf16 (64 B rows) = 128 KB.
//
// Bank-conflict-free chunk rotation: row r's global 16B chunk g lives at LDS
// chunk (g + (r>>1)) & 3. A frag read (32 rows x same chunk per half-wave)
// then covers all 8 bank-slots evenly -> minimum LDS service time.
// global_load_lds keeps a LINEAR dest; the *global source* chunk is inverse-
// rotated (both-sides-or-neither rule).
//
// Schedule: 8 phases / 2 K-tiles, ONE barrier per phase:
//   phase = { ds_read frags; stage 1 region; [vmcnt(8) on even]; barrier;
//             setprio(1); 8 MFMA; setprio(0) }
// Race-freedom: every staged region was last ds_read exactly 2 phases
// earlier; the reader's reads complete (lgkm) before its MFMAs, which precede
// it reaching the intervening barrier, which the stager passes before its
// stage issues. vmcnt(8) at even phases always waits only on loads issued
// >= 4 phases earlier (coverage verified for first, steady, tail iters).
// ---------------------------------------------------------------------------
template <bool OUTF>
__global__ __launch_bounds__(512) void gemm256_kernel(
    const ushort_t* __restrict__ A,
    const ushort_t* __restrict__ W0, const ushort_t* __restrict__ W1, const ushort_t* __restrict__ W2,
    const float* __restrict__ b0, const float* __restrict__ b1, const float* __restrict__ b2,
    void* __restrict__ C0, void* __restrict__ C1, void* __restrict__ C2,
    float s0, float s1, float s2, int N, int K)
{
    const ushort_t* W = (blockIdx.z == 0) ? W0 : ((blockIdx.z == 1) ? W1 : W2);
    const float* bias = (blockIdx.z == 0) ? b0 : ((blockIdx.z == 1) ? b1 : b2);
    void* C = (blockIdx.z == 0) ? C0 : ((blockIdx.z == 1) ? C1 : C2);
    const float scale = (blockIdx.z == 0) ? s0 : ((blockIdx.z == 1) ? s1 : s2);

    // [buf][region: 0=A-k0, 1=A-k1, 2=B-k0, 3=B-k1][256 rows x 32 k] bf16
    __shared__ ushort_t lds[2][4][256 * 32];

    const int tid = threadIdx.x;
    const int lane = tid & 63;
    const int wave = tid >> 6;
    const int wr = wave >> 2;       // 0..1 (M)
    const int wc = wave & 3;        // 0..3 (N)
    const int r32 = lane & 31;
    const int g = lane >> 5;        // k-half of fragment

    // XCD-aware bijective swizzle over the (x,y) plane (nwg % 8 == 0)
    const int gx = gridDim.x;
    const int flat = blockIdx.y * gx + blockIdx.x;
    const int cpx = (gx * gridDim.y) >> 3;
    const int swz = (flat & 7) * cpx + (flat >> 3);
    const int bm = (swz % gx) * 256;
    const int bn = (swz / gx) * 256;

    const ushort_t* Ag = A + (size_t)bm * K;
    const ushort_t* Bg = W + (size_t)bn * K;

    // staging: 1024 16B chunks per region; LDS chunk q -> row q>>2, slot q&3;
    // global source chunk = (slot - (row>>1)) & 3 (inverse rotation), coalesced
    // 64B per row.
    const int q0 = tid, q1 = 512 + tid;
    const int sr0 = q0 >> 2, sc0 = (((q0 & 3) - (sr0 >> 1)) & 3) * 8;
    const int sr1 = q1 >> 2, sc1 = (((q1 & 3) - (sr1 >> 1)) & 3) * 8;

#define STG(gbase, kcol, dst) do { \
    glds16((gbase) + (size_t)sr0 * K + (kcol) + sc0, (dst) + q0 * 8); \
    glds16((gbase) + (size_t)sr1 * K + (kcol) + sc1, (dst) + q1 * 8); } while (0)

#define BARRIER() do { \
    __builtin_amdgcn_sched_barrier(0); \
    asm volatile("s_barrier" ::: "memory"); \
    __builtin_amdgcn_sched_barrier(0); } while (0)

#define VMCNT(n) asm volatile("s_waitcnt vmcnt(" #n ")" ::: "memory")

    // rotated read offset (elements) for row r, logical chunk c
#define ROT(r, c) (((((c) + ((r) >> 1)) & 3)) * 8)

    f32x16 acc[4][2] = {};
    bf16x8 af[2][2], bfr[2][2];

#define LDA(buf, kh, mh) do { _Pragma("unroll") \
    for (int i = 0; i < 2; ++i) { _Pragma("unroll") \
        for (int t = 0; t < 2; ++t) { \
            int row = wr * 128 + ((mh) * 2 + i) * 32 + r32; \
            af[i][t] = *(const bf16x8*)(&lds[buf][kh][0] + row * 32 + ROT(row, 2 * t + g)); \
        } } } while (0)
#define LDB(buf, kh) do { _Pragma("unroll") \
    for (int ni = 0; ni < 2; ++ni) { _Pragma("unroll") \
        for (int t = 0; t < 2; ++t) { \
            int row = wc * 64 + ni * 32 + r32; \
            bfr[ni][t] = *(const bf16x8*)(&lds[buf][2 + (kh)][0] + row * 32 + ROT(row, 2 * t + g)); \
        } } } while (0)
#define MM(mh) do { __builtin_amdgcn_s_setprio(1); _Pragma("unroll") \
    for (int i = 0; i < 2; ++i) { _Pragma("unroll") \
        for (int ni = 0; ni < 2; ++ni) { \
            acc[(mh) * 2 + i][ni] = MFMA32(af[i][0], bfr[ni][0], acc[(mh) * 2 + i][ni]); \
            acc[(mh) * 2 + i][ni] = MFMA32(af[i][1], bfr[ni][1], acc[(mh) * 2 + i][ni]); \
        } } \
    __builtin_amdgcn_s_setprio(0); } while (0)

    // prologue: tile0 all 4 regions (buf0) + tile1 k0 regions (buf1)
    STG(Ag, 0,  &lds[0][0][0]);
    STG(Bg, 0,  &lds[0][2][0]);
    STG(Ag, 32, &lds[0][1][0]);
    STG(Bg, 32, &lds[0][3][0]);
    STG(Bg, 64, &lds[1][2][0]);
    STG(Ag, 64, &lds[1][0][0]);
    VMCNT(4);               // tile0 fully landed; tile1-k0 still in flight
    BARRIER();

#pragma unroll 1
    for (int i = 0; i < 7; ++i) {
        const int t = 2 * i;
        const int kc1 = (t + 1) * 64, kc2 = (t + 2) * 64, kc3 = (t + 3) * 64;
        // P1: t.k0 mh0 | stage buf1.Bk1 <- (t+1).k1
        LDB(0, 0); LDA(0, 0, 0);
        STG(Bg, kc1 + 32, &lds[1][3][0]);
        BARRIER(); MM(0);
        // P2: t.k0 mh1 | stage buf1.Ak1
        LDA(0, 0, 1);
        STG(Ag, kc1 + 32, &lds[1][1][0]);
        VMCNT(8);
        BARRIER(); MM(1);
        // P3: t.k1 mh0 | stage buf0.Bk0 <- (t+2).k0
        LDB(0, 1); LDA(0, 1, 0);
        STG(Bg, kc2, &lds[0][2][0]);
        BARRIER(); MM(0);
        // P4: t.k1 mh1 | stage buf0.Ak0
        LDA(0, 1, 1);
        STG(Ag, kc2, &lds[0][0][0]);
        VMCNT(8);
        BARRIER(); MM(1);
        // P5: (t+1).k0 mh0 | stage buf0.Bk1 <- (t+2).k1
        LDB(1, 0); LDA(1, 0, 0);
        STG(Bg, kc2 + 32, &lds[0][3][0]);
        BARRIER(); MM(0);
        // P6: (t+1).k0 mh1 | stage buf0.Ak1
        LDA(1, 0, 1);
        STG(Ag, kc2 + 32, &lds[0][1][0]);
        VMCNT(8);
        BARRIER(); MM(1);
        // P7: (t+1).k1 mh0 | stage buf1.Bk0 <- (t+3).k0
        LDB(1, 1); LDA(1, 1, 0);
        STG(Bg, kc3, &lds[1][2][0]);
        BARRIER(); MM(0);
        // P8: (t+1).k1 mh1 | stage buf1.Ak0
        LDA(1, 1, 1);
        STG(Ag, kc3, &lds[1][0][0]);
        VMCNT(8);
        BARRIER(); MM(1);
    }

    // tail: tiles 14 (buf0) and 15 (buf1); only t15.k1 still needs staging
    {
        const int kc15 = 15 * 64;
        LDB(0, 0); LDA(0, 0, 0);
        STG(Bg, kc15 + 32, &lds[1][3][0]);
        BARRIER(); MM(0);
        LDA(0, 0, 1);
        STG(Ag, kc15 + 32, &lds[1][1][0]);
        VMCNT(8);
        BARRIER(); MM(1);
        LDB(0, 1); LDA(0, 1, 0);
        BARRIER(); MM(0);
        LDA(0, 1, 1);
        VMCNT(0);           // all stages globally visible after this barrier
        BARRIER(); MM(1);
        // tile 15: everything resident, no further writes -> barrier-free
        LDB(1, 0); LDA(1, 0, 0); MM(0);
        LDA(1, 0, 1); MM(1);
        LDB(1, 1); LDA(1, 1, 0); MM(0);
        LDA(1, 1, 1); MM(1);
    }

    // epilogue: 32x32 C/D layout col = lane&31, row = (reg&3)+8*(reg>>2)+4*g
#pragma unroll
    for (int ni = 0; ni < 2; ++ni) {
        const int col = bn + wc * 64 + ni * 32 + r32;
        const float bv = bias[col];
#pragma unroll
        for (int mi = 0; mi < 4; ++mi) {
            const int rbase = bm + wr * 128 + mi * 32 + 4 * g;
#pragma unroll
            for (int reg = 0; reg < 16; ++reg) {
                const int row = rbase + (reg & 3) + 8 * (reg >> 2);
                float v = (acc[mi][ni][reg] + bv) * scale;
                if (OUTF)
                    ((float*)C)[(size_t)row * N + col] = v;
                else
                    ((ushort_t*)C)[(size_t)row * N + col] = f2b(v);
            }
        }
    }
#undef STG
#undef BARRIER
#undef VMCNT
#undef ROT
#undef LDA
#undef LDB
#undef MM
}

// ---------------------------------------------------------------------------
// V transpose: V[b*1024+s][h*64+d] -> Vt[(b*16+h)*64+d][s]  (bf16)
// ---------------------------------------------------------------------------
__global__ __launch_bounds__(256, 4) void transpose_v_kernel(
    const ushort_t* __restrict__ V, ushort_t* __restrict__ Vt)
{
    __shared__ ushort_t t[64 * 65];
    const int bh = blockIdx.x;
    const int st = blockIdx.y;
    const int b = bh >> 4, h = bh & 15;
    const int tid = threadIdx.x;

#pragma unroll
    for (int i = 0; i < 16; ++i) {
        int e = i * 256 + tid;
        int s = e >> 6, d = e & 63;
        t[s * 65 + d] = V[(size_t)(b * 1024 + st * 64 + s) * 1024 + h * 64 + d];
    }
    __syncthreads();
#pragma unroll
    for (int i = 0; i < 16; ++i) {
        int e = i * 256 + tid;
        int d = e >> 6, s = e & 63;
        Vt[(size_t)(bh * 64 + d) * 1024 + st * 64 + s] = t[s * 65 + d];
    }
}

// ---------------------------------------------------------------------------
// Attention v5: per block (bh, qtile of 128 rows). 4 waves x 32 q-rows
// (parallel m-groups). Double-buffered K/V staging. Row sums via MFMA
// against a constant all-ones B fragment. Q pre-scaled by log2(e)/8.
// ---------------------------------------------------------------------------
__global__ __launch_bounds__(256, 2) void attn_kernel(
    const ushort_t* __restrict__ Q, const ushort_t* __restrict__ K,
    const ushort_t* __restrict__ Vt, ushort_t* __restrict__ ctx)
{
    __shared__ ushort_t Ks[2][64 * 64];     // [kv][d] swizzled chunks
    __shared__ ushort_t Vs[2][64 * 64];     // [d][kv] swizzled chunks
    __shared__ ushort_t Ps[4][32 * 72];     // per-wave P: [m 0..31][k 0..63]

    const int bh = blockIdx.x;   // 0..255
    const int qt = blockIdx.y;   // 0..7
    const int b = bh >> 4, h = bh & 15;
    const int tid = threadIdx.x;
    const int lane = tid & 63;
    const int wave = tid >> 6;
    const int q = lane >> 4;
    const int ml = lane & 15;

    const int cid0 = tid;            // staging chunk ids
    const int cid1 = 256 + tid;
    const int r0 = cid0 >> 3, sc0 = (cid0 & 7) ^ (r0 & 7);
    const int r1 = cid1 >> 3, sc1 = (cid1 & 7) ^ (r1 & 7);
    const ushort_t* Kbase = K + (size_t)(b * 1024) * 1024 + h * 64;
    const ushort_t* Vbase = Vt + (size_t)(bh * 64) * 1024;

    // Q fragments (B operand of S^T mfma)
    bf16x8 qf[2][2];
#pragma unroll
    for (int mg = 0; mg < 2; ++mg) {
        int row = b * 1024 + qt * 128 + wave * 32 + mg * 16 + ml;
        const ushort_t* qp = Q + (size_t)row * 1024 + h * 64;
        qf[mg][0] = *(const bf16x8*)(qp + q * 8);
        qf[mg][1] = *(const bf16x8*)(qp + 32 + q * 8);
    }

    bf16x8 ones;
#pragma unroll
    for (int i = 0; i < 8; ++i) ones[i] = (short)0x3F80;  // bf16 1.0

    f32x4 o[2][4] = {};
    f32x4 ls[2] = {};
    ushort_t* Pw = Ps[wave];

    // prologue: stage kt=0 into buffer 0
    glds16(Kbase + (size_t)r0 * 1024 + sc0 * 8, Ks[0] + cid0 * 8);
    glds16(Vbase + (size_t)r0 * 1024 + sc0 * 8, Vs[0] + cid0 * 8);
    glds16(Kbase + (size_t)r1 * 1024 + sc1 * 8, Ks[0] + cid1 * 8);
    glds16(Vbase + (size_t)r1 * 1024 + sc1 * 8, Vs[0] + cid1 * 8);

    for (int kt = 0; kt < 16; ++kt) {
        const int cur = kt & 1, nxt = cur ^ 1;
        __syncthreads();   // drains this wave's loads for buf[cur]
        if (kt + 1 < 16) {
            const ushort_t* Kn = Kbase + (size_t)(kt + 1) * 64 * 1024;
            const ushort_t* Vn = Vbase + (kt + 1) * 64;
            glds16(Kn + (size_t)r0 * 1024 + sc0 * 8, Ks[nxt] + cid0 * 8);
            glds16(Vn + (size_t)r0 * 1024 + sc0 * 8, Vs[nxt] + cid0 * 8);
            glds16(Kn + (size_t)r1 * 1024 + sc1 * 8, Ks[nxt] + cid1 * 8);
            glds16(Vn + (size_t)r1 * 1024 + sc1 * 8, Vs[nxt] + cid1 * 8);
        }
        const ushort_t* Kc = Ks[cur];
        const ushort_t* Vc = Vs[cur];

        // S^T = K Q^T: C col=m(=ml), row=k_local=q*4+r
#pragma unroll
        for (int n = 0; n < 4; ++n) {
            int row = n * 16 + ml;
            int c0 = q ^ (row & 7);
            int c1 = (4 + q) ^ (row & 7);
            bf16x8 k0 = *(const bf16x8*)(Kc + row * 64 + c0 * 8);
            bf16x8 k1 = *(const bf16x8*)(Kc + row * 64 + c1 * 8);
#pragma unroll
            for (int mg = 0; mg < 2; ++mg) {
                f32x4 z = {};
                z = MFMA16(k0, qf[mg][0], z);
                z = MFMA16(k1, qf[mg][1], z);
                float p0 = __builtin_amdgcn_exp2f(z[0]);
                float p1 = __builtin_amdgcn_exp2f(z[1]);
                float p2 = __builtin_amdgcn_exp2f(z[2]);
                float p3 = __builtin_amdgcn_exp2f(z[3]);
                __hip_bfloat162 h01 = __float22bfloat162_rn(make_float2(p0, p1));
                __hip_bfloat162 h23 = __float22bfloat162_rn(make_float2(p2, p3));
                uint2 dd;
                __builtin_memcpy(&dd.x, &h01, 4);
                __builtin_memcpy(&dd.y, &h23, 4);
                *(uint2*)(Pw + (mg * 16 + ml) * 72 + n * 16 + q * 4) = dd;
            }
        }

        // P A-frags + PV + ones-sum
#pragma unroll
        for (int mg = 0; mg < 2; ++mg) {
            bf16x8 pf0 = *(const bf16x8*)(Pw + (mg * 16 + ml) * 72 + q * 8);
            bf16x8 pf1 = *(const bf16x8*)(Pw + (mg * 16 + ml) * 72 + 32 + q * 8);
            ls[mg] = MFMA16(pf0, ones, ls[mg]);
            ls[mg] = MFMA16(pf1, ones, ls[mg]);
#pragma unroll
            for (int n = 0; n < 4; ++n) {
                int row = n * 16 + ml;
                int c0 = q ^ (row & 7);
                int c1 = (4 + q) ^ (row & 7);
                bf16x8 v0 = *(const bf16x8*)(Vc + row * 64 + c0 * 8);
                bf16x8 v1 = *(const bf16x8*)(Vc + row * 64 + c1 * 8);
                o[mg][n] = MFMA16(pf0, v0, o[mg][n]);
                o[mg][n] = MFMA16(pf1, v1, o[mg][n]);
            }
        }
    }

    // normalize: ls[mg][r] is the full row sum for m=q*4+r — in-lane.
    const int orow_base = b * 1024 + qt * 128 + wave * 32;
#pragma unroll
    for (int mg = 0; mg < 2; ++mg) {
#pragma unroll
        for (int r = 0; r < 4; ++r) {
            float lv = 1.0f / ls[mg][r];
            int orow = orow_base + mg * 16 + q * 4 + r;
#pragma unroll
            for (int n = 0; n < 4; ++n) {
                ctx[(size_t)orow * 1024 + h * 64 + n * 16 + ml] =
                    f2b(o[mg][n][r] * lv);
            }
        }
    }
}

// ---------------------------------------------------------------------------
extern "C" void kernel_launch(void* const* d_in, const int* in_sizes, int n_in,
                              void* d_out, int out_size, void* d_ws, size_t ws_size,
                              hipStream_t stream)
{
    const float* X  = (const float*)d_in[0];
    const float* Wq = (const float*)d_in[1];
    const float* bq = (const float*)d_in[2];
    const float* Wk = (const float*)d_in[3];
    const float* bk = (const float*)d_in[4];
    const float* Wv = (const float*)d_in[5];
    const float* bv = (const float*)d_in[6];
    const float* Wo = (const float*)d_in[7];
    const float* bo = (const float*)d_in[8];

    const int D = 1024;
    const int M = in_sizes[0] / D;       // 16384
    const int Bb = M / 1024;             // 16 batches
    const size_t MD = (size_t)M * D;
    const size_t DD = (size_t)D * D;

    ushort_t* ws  = (ushort_t*)d_ws;
    ushort_t* Xbf = ws;                  // -> reused as Vt after QKV
    ushort_t* Qb  = ws + MD;
    ushort_t* Kb  = ws + 2 * MD;
    ushort_t* Vb  = ws + 3 * MD;         // -> reused as ctx after transpose
    ushort_t* Wqb = ws + 4 * MD;
    ushort_t* Wkb = Wqb + DD;
    ushort_t* Wvb = Wkb + DD;
    ushort_t* Wob = Wvb + DD;
    ushort_t* Vtb = Xbf;
    ushort_t* ctx = Vb;

    dim3 blk(256);
    dim3 blk512(512);

    cvt1_kernel<<<(int)(MD / 8 / 256), blk, 0, stream>>>(X, Xbf, (int)(MD / 8));
    cvt4_kernel<<<dim3((int)(DD / 8 / 256), 4), blk, 0, stream>>>(
        Wq, Wk, Wv, Wo, Wqb, Wkb, Wvb, Wob, (int)(DD / 8));

    // Q pre-scaled by log2(e)/sqrt(64) so attention uses exp2 directly.
    const float qscale = 1.4426950408889634f * 0.125f;
    dim3 gqkv(M / 256, D / 256, 3);
    gemm256_kernel<false><<<gqkv, blk512, 0, stream>>>(Xbf, Wqb, Wkb, Wvb,
                                                       bq, bk, bv,
                                                       Qb, Kb, Vb,
                                                       qscale, 1.0f, 1.0f, D, D);

    transpose_v_kernel<<<dim3(Bb * 16, 16), blk, 0, stream>>>(Vb, Vtb);

    attn_kernel<<<dim3(Bb * 16, 8), blk, 0, stream>>>(Qb, Kb, Vtb, ctx);

    dim3 go(M / 256, D / 256, 1);
    gemm256_kernel<true><<<go, blk512, 0, stream>>>(ctx, Wob, Wob, Wob,
                                                    bo, bo, bo,
                                                    d_out, d_out, d_out,
                                                    1.0f, 1.0f, 1.0f, D, D);
}